// Round 3
// baseline (335.472 us; speedup 1.0000x reference)
//
#include <hip/hip_runtime.h>

typedef __bf16 bf16x8 __attribute__((ext_vector_type(8)));
typedef float  f32x4  __attribute__((ext_vector_type(4)));

__device__ __forceinline__ unsigned short f2bf(float f) {
  unsigned int u = __builtin_bit_cast(unsigned int, f);
  u = u + 0x7fffu + ((u >> 16) & 1u);
  return (unsigned short)(u >> 16);
}

// ws layout (ushort elements):
//   W1b [256][256] @ 0        (row-major, N x K)
//   W2b [256][256] @ 65536
//   W3b [256][640] @ 131072
//   W4b [16][256]  @ 294912   (rows 8..15 zeroed)
#define O_W2 65536
#define O_W3 131072
#define O_W4 294912
#define N_PREP 299008

__global__ void prep_kernel(const float* __restrict__ W1, const float* __restrict__ W2,
                            const float* __restrict__ W3, const float* __restrict__ W4,
                            unsigned short* __restrict__ ws) {
  int id = blockIdx.x * 256 + threadIdx.x;
  if (id < O_W2) {
    ws[id] = f2bf(W1[id]);
  } else if (id < O_W3) {
    ws[id] = f2bf(W2[id - O_W2]);
  } else if (id < O_W4) {
    ws[id] = f2bf(W3[id - O_W3]);
  } else if (id < N_PREP) {
    int t = id - O_W4;
    ws[id] = (t < 2048) ? f2bf(W4[t]) : (unsigned short)0;
  }
}

// sbuf: [64][384] bf16 (state subtile: s0|s1|s2), row stride 768B.
// hy:   [64][256] bf16 (h_i, later y),            row stride 512B.
// Both strides are 0 mod 128B -> XOR-swizzle elem bits 3..5 with row&7.
#define SB(r, c) ((r) * 384 + ((c) ^ (((r) & 7) << 3)))
#define SH(r, c) ((r) * 256 + ((c) ^ (((r) & 7) << 3)))
#define MFMA __builtin_amdgcn_mfma_f32_16x16x32_bf16

__global__ __launch_bounds__(512, 2) void actor_kernel(
    const float* __restrict__ state,
    const float* __restrict__ b1, const float* __restrict__ b2,
    const float* __restrict__ b3, const float* __restrict__ b4,
    const unsigned short* __restrict__ wsb,
    float* __restrict__ out)
{
  __shared__ __align__(16) unsigned short sbuf[2][64 * 384];  // 96 KB
  __shared__ __align__(16) unsigned short hy[64 * 256];       // 32 KB

  const int tid  = threadIdx.x;
  const int w    = tid >> 6;     // wave 0..7
  const int lane = tid & 63;
  const int lr   = lane & 15;
  const int lg   = lane >> 4;
  const long blk = blockIdx.x;

  // ---- prologue: stage subtile 0 ----
  {
    const float4* sp = (const float4*)(state + blk * 256 * 384);
    #pragma unroll
    for (int i = 0; i < 12; ++i) {
      int f = tid + i * 512;
      float4 v = sp[f];
      int r = f / 96, rem = f - r * 96;
      ushort4 u;
      u.x = f2bf(v.x); u.y = f2bf(v.y); u.z = f2bf(v.z); u.w = f2bf(v.w);
      *(ushort4*)&sbuf[0][SB(r, rem * 4)] = u;
    }
  }
  __syncthreads();

  for (int t = 0; t < 4; ++t) {
    const int cur = t & 1, nxt = cur ^ 1;
    float4 sv[12];

    // ================= GEMM1 (U/V decomposition) =================
    // U  = s0 @ {W1,W2}[:, :128]^T   (K=128)
    // Vp = sp @ {W1,W2}[:, 128:]^T   (p=1,2 share weights)
    // h0=relu(U+V1+b1), h1=relu(U+V2+b1), e same with W2/b2; softmax combine.
    #pragma unroll 2
    for (int sc = 0; sc < 2; ++sc) {
      const int nH = (w * 2 + sc) * 16;   // this pass's 16-col slice (H and E)
      // preload all weights for this pass (16 x 16B, deep MLP)
      bf16x8 wa1[4], wa2[4], wb1[4], wb2[4];
      const unsigned short* p1 = wsb + (nH + lr) * 256 + lg * 8;
      const unsigned short* p2 = wsb + O_W2 + (nH + lr) * 256 + lg * 8;
      #pragma unroll
      for (int kk = 0; kk < 4; ++kk) {
        wa1[kk] = *(const bf16x8*)(p1 + kk * 32);
        wa2[kk] = *(const bf16x8*)(p2 + kk * 32);
        wb1[kk] = *(const bf16x8*)(p1 + 128 + kk * 32);
        wb2[kk] = *(const bf16x8*)(p2 + 128 + kk * 32);
      }
      const float bv1 = b1[nH + lr];
      const float bv2 = b2[nH + lr];

      f32x4 aUh[4], aUe[4], aV1h[4], aV1e[4], aV2h[4], aV2e[4];
      #pragma unroll
      for (int rt = 0; rt < 4; ++rt) {
        aUh[rt] = (f32x4){0.f,0.f,0.f,0.f};  aUe[rt] = (f32x4){0.f,0.f,0.f,0.f};
        aV1h[rt] = (f32x4){0.f,0.f,0.f,0.f}; aV1e[rt] = (f32x4){0.f,0.f,0.f,0.f};
        aV2h[rt] = (f32x4){0.f,0.f,0.f,0.f}; aV2e[rt] = (f32x4){0.f,0.f,0.f,0.f};
      }

      #pragma unroll
      for (int kk = 0; kk < 4; ++kk) {
        #pragma unroll
        for (int rt = 0; rt < 4; ++rt) {
          const int row = rt * 16 + lr;
          bf16x8 a0 = *(const bf16x8*)&sbuf[cur][SB(row, kk * 32 + lg * 8)];
          aUh[rt] = MFMA(a0, wa1[kk], aUh[rt], 0, 0, 0);
          aUe[rt] = MFMA(a0, wa2[kk], aUe[rt], 0, 0, 0);
          bf16x8 a1 = *(const bf16x8*)&sbuf[cur][SB(row, 128 + kk * 32 + lg * 8)];
          aV1h[rt] = MFMA(a1, wb1[kk], aV1h[rt], 0, 0, 0);
          aV1e[rt] = MFMA(a1, wb2[kk], aV1e[rt], 0, 0, 0);
          bf16x8 a2 = *(const bf16x8*)&sbuf[cur][SB(row, 256 + kk * 32 + lg * 8)];
          aV2h[rt] = MFMA(a2, wb1[kk], aV2h[rt], 0, 0, 0);
          aV2e[rt] = MFMA(a2, wb2[kk], aV2e[rt], 0, 0, 0);
        }
      }

      // issue next-subtile state loads AFTER all GEMM1 weight loads (in-order
      // vmcnt: later waits won't drain these) — hidden under combine + barrier.
      if (sc == 1 && t < 3) {
        const float4* sp = (const float4*)(state + (blk * 256 + (t + 1) * 64) * 384);
        #pragma unroll
        for (int i = 0; i < 12; ++i) sv[i] = sp[tid + i * 512];
      }

      // combine: D row = lg*4+reg, col = lr
      #pragma unroll
      for (int rt = 0; rt < 4; ++rt) {
        #pragma unroll
        for (int reg = 0; reg < 4; ++reg) {
          const int r = rt * 16 + lg * 4 + reg;
          float uh = aUh[rt][reg], ue = aUe[rt][reg];
          float h0 = fmaxf(uh + aV1h[rt][reg] + bv1, 0.f);
          float h1 = fmaxf(uh + aV2h[rt][reg] + bv1, 0.f);
          float e0 = fmaxf(ue + aV1e[rt][reg] + bv2, 0.f);
          float e1 = fmaxf(ue + aV2e[rt][reg] + bv2, 0.f);
          float a0w = 1.0f / (1.0f + __expf(e1 - e0));
          hy[SH(r, nH + lr)] = f2bf(h1 + a0w * (h0 - h1));
        }
      }
    }
    __syncthreads();   // b1: h ready (GEMM3 reads it)

    // write staged state (loads have had all of GEMM1 to land)
    if (t < 3) {
      #pragma unroll
      for (int i = 0; i < 12; ++i) {
        int f = tid + i * 512;
        int r = f / 96, rem = f - r * 96;
        ushort4 u;
        u.x = f2bf(sv[i].x); u.y = f2bf(sv[i].y); u.z = f2bf(sv[i].z); u.w = f2bf(sv[i].w);
        *(ushort4*)&sbuf[nxt][SB(r, rem * 4)] = u;
      }
    }

    // ================= GEMM3: [h|s] (64x640) @ W3^T =================
    {
      const int n3 = w * 32;
      const unsigned short* w3p = wsb + O_W3 + (n3 + lr) * 640 + lg * 8;
      const float bv3a = b3[n3 + lr];
      const float bv3b = b3[n3 + 16 + lr];
      bf16x8 ring[4][2];
      #pragma unroll
      for (int k = 0; k < 3; ++k) {
        ring[k][0] = *(const bf16x8*)(w3p + k * 32);
        ring[k][1] = *(const bf16x8*)(w3p + 16 * 640 + k * 32);
      }
      f32x4 acc3[4][2];
      #pragma unroll
      for (int rt = 0; rt < 4; ++rt) {
        acc3[rt][0] = (f32x4){0.f,0.f,0.f,0.f};
        acc3[rt][1] = (f32x4){0.f,0.f,0.f,0.f};
      }
      // ks 0..7: A from hy (h region)
      #pragma unroll 4
      for (int ks = 0; ks < 8; ++ks) {
        ring[(ks + 3) & 3][0] = *(const bf16x8*)(w3p + (ks + 3) * 32);
        ring[(ks + 3) & 3][1] = *(const bf16x8*)(w3p + 16 * 640 + (ks + 3) * 32);
        #pragma unroll
        for (int rt = 0; rt < 4; ++rt) {
          bf16x8 a = *(const bf16x8*)&hy[SH(rt * 16 + lr, ks * 32 + lg * 8)];
          acc3[rt][0] = MFMA(a, ring[ks & 3][0], acc3[rt][0], 0, 0, 0);
          acc3[rt][1] = MFMA(a, ring[ks & 3][1], acc3[rt][1], 0, 0, 0);
        }
      }
      // ks 8..19: A from sbuf[cur] (state region)
      #pragma unroll 4
      for (int ks = 8; ks < 20; ++ks) {
        if (ks < 17) {
          ring[(ks + 3) & 3][0] = *(const bf16x8*)(w3p + (ks + 3) * 32);
          ring[(ks + 3) & 3][1] = *(const bf16x8*)(w3p + 16 * 640 + (ks + 3) * 32);
        }
        #pragma unroll
        for (int rt = 0; rt < 4; ++rt) {
          bf16x8 a = *(const bf16x8*)&sbuf[cur][SB(rt * 16 + lr, (ks - 8) * 32 + lg * 8)];
          acc3[rt][0] = MFMA(a, ring[ks & 3][0], acc3[rt][0], 0, 0, 0);
          acc3[rt][1] = MFMA(a, ring[ks & 3][1], acc3[rt][1], 0, 0, 0);
        }
      }
      __syncthreads();   // b2: all reads of hy done; safe to overwrite with y
      #pragma unroll
      for (int rt = 0; rt < 4; ++rt) {
        #pragma unroll
        for (int reg = 0; reg < 4; ++reg) {
          const int row = rt * 16 + lg * 4 + reg;
          hy[SH(row, n3 + lr)]      = f2bf(fmaxf(acc3[rt][0][reg] + bv3a, 0.f));
          hy[SH(row, n3 + 16 + lr)] = f2bf(fmaxf(acc3[rt][1][reg] + bv3b, 0.f));
        }
      }
    }
    __syncthreads();   // b3: y ready

    // ================= GEMM4: y(64x256) @ W4^T, tanh =================
    if (w < 4) {
      f32x4 acc4 = (f32x4){0.f,0.f,0.f,0.f};
      const unsigned short* w4p = wsb + O_W4 + lr * 256 + lg * 8;
      #pragma unroll
      for (int ks = 0; ks < 8; ++ks) {
        bf16x8 a = *(const bf16x8*)&hy[SH(w * 16 + lr, ks * 32 + lg * 8)];
        bf16x8 b = *(const bf16x8*)(w4p + ks * 32);
        acc4 = MFMA(a, b, acc4, 0, 0, 0);
      }
      if (lr < 8) {
        const float b4v = b4[lr];
        #pragma unroll
        for (int reg = 0; reg < 4; ++reg) {
          float x = acc4[reg] + b4v;
          float z = __expf(-2.f * fabsf(x));
          float tv = (1.f - z) / (1.f + z);
          long row = blk * 256 + t * 64 + w * 16 + lg * 4 + reg;
          out[row * 8 + lr] = copysignf(tv, x);
        }
      }
    }
    __syncthreads();   // b4: GEMM4 done reading hy; next subtile may rewrite
  }
}

extern "C" void kernel_launch(void* const* d_in, const int* in_sizes, int n_in,
                              void* d_out, int out_size, void* d_ws, size_t ws_size,
                              hipStream_t stream) {
  const float* state = (const float*)d_in[0];
  const float* W1 = (const float*)d_in[1];
  const float* b1 = (const float*)d_in[2];
  const float* W2 = (const float*)d_in[3];
  const float* b2 = (const float*)d_in[4];
  const float* W3 = (const float*)d_in[5];
  const float* b3 = (const float*)d_in[6];
  const float* W4 = (const float*)d_in[7];
  const float* b4 = (const float*)d_in[8];

  unsigned short* wsb = (unsigned short*)d_ws;

  prep_kernel<<<(N_PREP + 255) / 256, 256, 0, stream>>>(W1, W2, W3, W4, wsb);
  actor_kernel<<<256, 512, 0, stream>>>(state, b1, b2, b3, b4, wsb, (float*)d_out);
}

// Round 4
// 237.286 us; speedup vs baseline: 1.4138x; 1.4138x over previous
//
#include <hip/hip_runtime.h>

typedef __bf16 bf16x8 __attribute__((ext_vector_type(8)));
typedef float  f32x4  __attribute__((ext_vector_type(4)));

__device__ __forceinline__ unsigned short f2bf(float f) {
  unsigned int u = __builtin_bit_cast(unsigned int, f);
  u = u + 0x7fffu + ((u >> 16) & 1u);
  return (unsigned short)(u >> 16);
}

// ws layout (ushort elements):
//   W1b [256][256] @ 0        (row-major, N x K)
//   W2b [256][256] @ 65536
//   W3b [256][640] @ 131072
//   W4b [16][256]  @ 294912   (rows 8..15 zeroed)
#define O_W2 65536
#define O_W3 131072
#define O_W4 294912
#define N_PREP 299008

__global__ void prep_kernel(const float* __restrict__ W1, const float* __restrict__ W2,
                            const float* __restrict__ W3, const float* __restrict__ W4,
                            unsigned short* __restrict__ ws) {
  int id = blockIdx.x * 256 + threadIdx.x;
  if (id < O_W2) {
    ws[id] = f2bf(W1[id]);
  } else if (id < O_W3) {
    ws[id] = f2bf(W2[id - O_W2]);
  } else if (id < O_W4) {
    ws[id] = f2bf(W3[id - O_W3]);
  } else if (id < N_PREP) {
    int t = id - O_W4;
    ws[id] = (t < 2048) ? f2bf(W4[t]) : (unsigned short)0;
  }
}

// xxx: 64 rows x 640 cols bf16 = 80 KB exactly -> 2 blocks/CU.
// cols [0,256) = h_i (later y), cols [256,640) = state row (s0|s1|s2) bf16.
// XOR swizzle elem bits 3..5 with row&7 (byte bits 4..6): 8-row groups land in
// distinct 16B slots -> worst case 2-way (free) on all b128 reads.
#define SX(r, c) ((r) * 640 + ((c) ^ (((r) & 7) << 3)))
#define MFMA __builtin_amdgcn_mfma_f32_16x16x32_bf16

__global__ __launch_bounds__(512, 4) void actor_kernel(
    const float* __restrict__ state,
    const float* __restrict__ b1, const float* __restrict__ b2,
    const float* __restrict__ b3, const float* __restrict__ b4,
    const unsigned short* __restrict__ wsb,
    float* __restrict__ out)
{
  __shared__ __align__(16) unsigned short xxx[64 * 640];   // 80 KB

  const int tid  = threadIdx.x;
  const int w    = tid >> 6;     // wave 0..7
  const int lane = tid & 63;
  const int lr   = lane & 15;
  const int lg   = lane >> 4;
  const long b0  = (long)blockIdx.x * 64;

  // ---- Phase 0: stage 64 state rows (64x384 f32) into cols [256,640) as bf16 ----
  {
    const float4* sp = (const float4*)(state + b0 * 384);
    #pragma unroll
    for (int i = 0; i < 12; ++i) {
      int f = tid + i * 512;             // float4 index, < 6144
      float4 v = sp[f];
      int r = f / 96, rem = f - r * 96;  // rem in [0,96)
      ushort4 u;
      u.x = f2bf(v.x); u.y = f2bf(v.y); u.z = f2bf(v.z); u.w = f2bf(v.w);
      *(ushort4*)&xxx[SX(r, 256 + rem * 4)] = u;
    }
  }
  __syncthreads();

  // ---- GEMM1: agents(128x256) @ {W1,W2}^T + bias, relu, softmax -> h cols [0,256) ----
  // Wave owns H cols [w*32,+32) AND E cols [w*32,+32); 4 passes of 8 cols each.
  // B-frag packs H in lanes lr<8 (from W1) and E in lanes lr>=8 (from W2):
  // one MFMA produces both; shfl_xor(8) pairs them for the softmax combine.
  #pragma unroll 1
  for (int p = 0; p < 4; ++p) {
    const int cb = w * 32 + p * 8;
    const unsigned short* wp = (lr < 8)
        ? (wsb + (cb + lr) * 256 + lg * 8)
        : (wsb + O_W2 + (cb + (lr - 8)) * 256 + lg * 8);
    const float bv1 = b1[cb + (lr & 7)];
    const float bv2 = b2[cb + (lr & 7)];

    bf16x8 ring[4];
    ring[0] = *(const bf16x8*)(wp);
    ring[1] = *(const bf16x8*)(wp + 32);
    ring[2] = *(const bf16x8*)(wp + 64);

    f32x4 acc[8];
    #pragma unroll
    for (int rt = 0; rt < 8; ++rt) acc[rt] = (f32x4){0.f, 0.f, 0.f, 0.f};

    // A row m = rt*16+lr (agent index): r=m>>1=rt*8+(lr>>1), agent=(lr&1).
    // k<128 -> s0 (cols 256+k, broadcast across the lane pair);
    // k>=128 -> s[1+agent] (cols 384+agent*128+k-128).
    #pragma unroll
    for (int ks = 0; ks < 8; ++ks) {
      if (ks < 5) ring[(ks + 3) & 3] = *(const bf16x8*)(wp + (ks + 3) * 32);
      const int colk = (ks < 4) ? (256 + ks * 32 + lg * 8)
                                : (384 + ((lr & 1) << 7) + (ks - 4) * 32 + lg * 8);
      #pragma unroll
      for (int rt = 0; rt < 8; ++rt) {
        const int r = rt * 8 + (lr >> 1);
        bf16x8 a = *(const bf16x8*)&xxx[SX(r, colk)];
        acc[rt] = MFMA(a, ring[ks & 3], acc[rt], 0, 0, 0);
      }
    }

    // combine: D row = rt*16+lg*4+reg (agent idx), col = cb+(lr&7).
    // reg=2q+pa -> state row r = rt*8+lg*2+q, agent pa.
    #pragma unroll
    for (int rt = 0; rt < 8; ++rt) {
      float o0 = __shfl_xor(acc[rt][0], 8);
      float o1 = __shfl_xor(acc[rt][1], 8);
      float o2 = __shfl_xor(acc[rt][2], 8);
      float o3 = __shfl_xor(acc[rt][3], 8);
      #pragma unroll
      for (int q = 0; q < 2; ++q) {
        // valid on lanes lr<8 only (acc=H, oth=E); lr>=8 computes discard.
        float h0 = fmaxf(acc[rt][2 * q + 0] + bv1, 0.f);
        float h1 = fmaxf(acc[rt][2 * q + 1] + bv1, 0.f);
        float e0 = fmaxf((q ? o2 : o0) + bv2, 0.f);
        float e1 = fmaxf((q ? o3 : o1) + bv2, 0.f);
        float a0w = 1.0f / (1.0f + __expf(e1 - e0));
        float hi = h1 + a0w * (h0 - h1);
        if (lr < 8) {
          const int r = rt * 8 + lg * 2 + q;
          xxx[SX(r, cb + lr)] = f2bf(hi);
        }
      }
    }
  }
  __syncthreads();   // h ready

  // ---- GEMM3: [h|s](64x640) @ W3^T + b3, relu -> y (overwrites h region) ----
  {
    const int n3 = w * 32;
    const unsigned short* w3p = wsb + O_W3 + (n3 + lr) * 640 + lg * 8;
    const float bv3a = b3[n3 + lr];
    const float bv3b = b3[n3 + 16 + lr];

    bf16x8 ring3[4][2];
    #pragma unroll
    for (int k = 0; k < 3; ++k) {
      ring3[k][0] = *(const bf16x8*)(w3p + k * 32);
      ring3[k][1] = *(const bf16x8*)(w3p + 16 * 640 + k * 32);
    }
    f32x4 acc3[4][2];
    #pragma unroll
    for (int rt = 0; rt < 4; ++rt) {
      acc3[rt][0] = (f32x4){0.f, 0.f, 0.f, 0.f};
      acc3[rt][1] = (f32x4){0.f, 0.f, 0.f, 0.f};
    }
    #pragma unroll 4
    for (int ks = 0; ks < 20; ++ks) {
      if (ks < 17) {
        ring3[(ks + 3) & 3][0] = *(const bf16x8*)(w3p + (ks + 3) * 32);
        ring3[(ks + 3) & 3][1] = *(const bf16x8*)(w3p + 16 * 640 + (ks + 3) * 32);
      }
      #pragma unroll
      for (int rt = 0; rt < 4; ++rt) {
        bf16x8 a = *(const bf16x8*)&xxx[SX(rt * 16 + lr, ks * 32 + lg * 8)];
        acc3[rt][0] = MFMA(a, ring3[ks & 3][0], acc3[rt][0], 0, 0, 0);
        acc3[rt][1] = MFMA(a, ring3[ks & 3][1], acc3[rt][1], 0, 0, 0);
      }
    }
    __syncthreads();   // all h reads done; safe to overwrite with y
    #pragma unroll
    for (int rt = 0; rt < 4; ++rt) {
      #pragma unroll
      for (int reg = 0; reg < 4; ++reg) {
        const int row = rt * 16 + lg * 4 + reg;
        xxx[SX(row, n3 + lr)]      = f2bf(fmaxf(acc3[rt][0][reg] + bv3a, 0.f));
        xxx[SX(row, n3 + 16 + lr)] = f2bf(fmaxf(acc3[rt][1][reg] + bv3b, 0.f));
      }
    }
  }
  __syncthreads();   // y ready

  // ---- GEMM4: y(64x256) @ W4^T (16 rows, 8 valid) + b4, tanh -> out ----
  if (w < 4) {
    f32x4 acc4 = (f32x4){0.f, 0.f, 0.f, 0.f};
    const unsigned short* w4p = wsb + O_W4 + lr * 256 + lg * 8;
    #pragma unroll
    for (int ks = 0; ks < 8; ++ks) {
      bf16x8 a = *(const bf16x8*)&xxx[SX(w * 16 + lr, ks * 32 + lg * 8)];
      bf16x8 b = *(const bf16x8*)(w4p + ks * 32);
      acc4 = MFMA(a, b, acc4, 0, 0, 0);
    }
    if (lr < 8) {
      const float b4v = b4[lr];
      #pragma unroll
      for (int reg = 0; reg < 4; ++reg) {
        float x = acc4[reg] + b4v;
        float z = __expf(-2.f * fabsf(x));
        float t = (1.f - z) / (1.f + z);
        long row = b0 + w * 16 + lg * 4 + reg;
        out[row * 8 + lr] = copysignf(t, x);
      }
    }
  }
}

extern "C" void kernel_launch(void* const* d_in, const int* in_sizes, int n_in,
                              void* d_out, int out_size, void* d_ws, size_t ws_size,
                              hipStream_t stream) {
  const float* state = (const float*)d_in[0];
  const float* W1 = (const float*)d_in[1];
  const float* b1 = (const float*)d_in[2];
  const float* W2 = (const float*)d_in[3];
  const float* b2 = (const float*)d_in[4];
  const float* W3 = (const float*)d_in[5];
  const float* b3 = (const float*)d_in[6];
  const float* W4 = (const float*)d_in[7];
  const float* b4 = (const float*)d_in[8];

  unsigned short* wsb = (unsigned short*)d_ws;

  prep_kernel<<<(N_PREP + 255) / 256, 256, 0, stream>>>(W1, W2, W3, W4, wsb);
  actor_kernel<<<1024, 512, 0, stream>>>(state, b1, b2, b3, b4, wsb, (float*)d_out);
}